// Round 1
// baseline (36.252 us; speedup 1.0000x reference)
//
#include <hip/hip_runtime.h>

// SelectDropMAX: x[B,C,H,W] f32, per-channel (B*C) 28x28 map.
// out = x - 0.9*x*mask, mask = (x == channel_max) | (7x2 block at (y0,x0)).
// Memory-bound: 103MB in + 103MB out. One 64-lane wave per channel,
// all data held in registers (3-4 float4 per lane), shuffle max-reduce.

constexpr int Hdim = 28;
constexpr int Wdim = 28;
constexpr int HW = Hdim * Wdim;   // 784
constexpr int NF4 = HW / 4;       // 196 float4 per channel
constexpr float SUPPRESS = 0.9f;

__global__ __launch_bounds__(256) void selectdropmax_kernel(
    const float* __restrict__ x,
    const int* __restrict__ mask_y,
    const int* __restrict__ mask_x,
    float* __restrict__ out,
    int nch)
{
    const int gtid = blockIdx.x * blockDim.x + threadIdx.x;
    const int ch   = gtid >> 6;          // one wave per channel
    const int lane = threadIdx.x & 63;
    if (ch >= nch) return;

    const float4* __restrict__ xp = reinterpret_cast<const float4*>(x) + (size_t)ch * NF4;
    float4* __restrict__ op       = reinterpret_cast<float4*>(out) + (size_t)ch * NF4;

    // Load: lane i takes float4 i, i+64, i+128; lanes 0..3 take 192+i.
    const bool extra = (lane < (NF4 - 192));   // lanes 0..3
    float4 v0 = xp[lane];
    float4 v1 = xp[lane + 64];
    float4 v2 = xp[lane + 128];
    float4 v3 = make_float4(0.f, 0.f, 0.f, 0.f);
    if (extra) v3 = xp[lane + 192];

    // Per-lane max
    float m = fmaxf(fmaxf(v0.x, v0.y), fmaxf(v0.z, v0.w));
    m = fmaxf(m, fmaxf(fmaxf(v1.x, v1.y), fmaxf(v1.z, v1.w)));
    m = fmaxf(m, fmaxf(fmaxf(v2.x, v2.y), fmaxf(v2.z, v2.w)));
    if (extra) m = fmaxf(m, fmaxf(fmaxf(v3.x, v3.y), fmaxf(v3.z, v3.w)));

    // 64-lane butterfly max reduce (exact: fp32 max of exact values)
    #pragma unroll
    for (int off = 32; off > 0; off >>= 1)
        m = fmaxf(m, __shfl_xor(m, off, 64));

    const int y0 = mask_y[ch];
    const int x0 = mask_x[ch];

    auto proc = [&](float4 v, int f4idx) -> float4 {
        float vals[4] = {v.x, v.y, v.z, v.w};
        float res[4];
        const int base = f4idx * 4;
        #pragma unroll
        for (int j = 0; j < 4; ++j) {
            const int idx = base + j;
            const int h = idx / Wdim;          // magic-mul, Wdim const
            const int w = idx - h * Wdim;
            const bool inblk = (h >= y0) & (h < y0 + 7) & (w >= x0) & (w < x0 + 2);
            const bool msk = (vals[j] == m) | inblk;
            // match ref rounding: x - (0.9*x); separate mul then sub
            const float t = SUPPRESS * vals[j];
            res[j] = msk ? (vals[j] - t) : vals[j];
        }
        return make_float4(res[0], res[1], res[2], res[3]);
    };

    op[lane]       = proc(v0, lane);
    op[lane + 64]  = proc(v1, lane + 64);
    op[lane + 128] = proc(v2, lane + 128);
    if (extra) op[lane + 192] = proc(v3, lane + 192);
}

extern "C" void kernel_launch(void* const* d_in, const int* in_sizes, int n_in,
                              void* d_out, int out_size, void* d_ws, size_t ws_size,
                              hipStream_t stream) {
    const float* x      = (const float*)d_in[0];
    const int*   mask_y = (const int*)d_in[1];
    const int*   mask_x = (const int*)d_in[2];
    float*       out    = (float*)d_out;

    const int nch = in_sizes[1];              // B*C = 32768
    const int waves_per_block = 4;            // 256 threads
    const int nblocks = (nch + waves_per_block - 1) / waves_per_block;

    hipLaunchKernelGGL(selectdropmax_kernel,
                       dim3(nblocks), dim3(256), 0, stream,
                       x, mask_y, mask_x, out, nch);
}

// Round 2
// 35.326 us; speedup vs baseline: 1.0262x; 1.0262x over previous
//
#include <hip/hip_runtime.h>

// SelectDropMAX: x[B,C,H,W] f32, per-channel (B*C) 28x28 map.
// out = x - 0.9*x*mask, mask = (x == channel_max) | (7x2 block at (y0,x0)).
// Memory-bound: 103MB in + 103MB out. One 64-lane wave per channel,
// all data held in registers (3-4 float4 per lane), shuffle max-reduce.
// R1: nontemporal output stores -> don't evict the L3-resident input.

constexpr int Hdim = 28;
constexpr int Wdim = 28;
constexpr int HW = Hdim * Wdim;   // 784
constexpr int NF4 = HW / 4;       // 196 float4 per channel
constexpr float SUPPRESS = 0.9f;

typedef float f4 __attribute__((ext_vector_type(4)));

__global__ __launch_bounds__(256) void selectdropmax_kernel(
    const float* __restrict__ x,
    const int* __restrict__ mask_y,
    const int* __restrict__ mask_x,
    float* __restrict__ out,
    int nch)
{
    const int gtid = blockIdx.x * blockDim.x + threadIdx.x;
    const int ch   = gtid >> 6;          // one wave per channel
    const int lane = threadIdx.x & 63;
    if (ch >= nch) return;

    const f4* __restrict__ xp = reinterpret_cast<const f4*>(x) + (size_t)ch * NF4;
    f4* __restrict__ op       = reinterpret_cast<f4*>(out) + (size_t)ch * NF4;

    // Load: lane i takes float4 i, i+64, i+128; lanes 0..3 take 192+i.
    const bool extra = (lane < (NF4 - 192));   // lanes 0..3
    f4 v0 = xp[lane];
    f4 v1 = xp[lane + 64];
    f4 v2 = xp[lane + 128];
    f4 v3 = (f4){0.f, 0.f, 0.f, 0.f};
    if (extra) v3 = xp[lane + 192];

    // Per-lane max
    float m = fmaxf(fmaxf(v0.x, v0.y), fmaxf(v0.z, v0.w));
    m = fmaxf(m, fmaxf(fmaxf(v1.x, v1.y), fmaxf(v1.z, v1.w)));
    m = fmaxf(m, fmaxf(fmaxf(v2.x, v2.y), fmaxf(v2.z, v2.w)));
    if (extra) m = fmaxf(m, fmaxf(fmaxf(v3.x, v3.y), fmaxf(v3.z, v3.w)));

    // 64-lane butterfly max reduce (exact: fp32 max of exact values)
    #pragma unroll
    for (int off = 32; off > 0; off >>= 1)
        m = fmaxf(m, __shfl_xor(m, off, 64));

    const int y0 = mask_y[ch];
    const int x0 = mask_x[ch];

    auto proc = [&](f4 v, int f4idx) -> f4 {
        f4 res;
        const int base = f4idx * 4;
        #pragma unroll
        for (int j = 0; j < 4; ++j) {
            const float val = v[j];
            const int idx = base + j;
            const int h = idx / Wdim;          // magic-mul, Wdim const
            const int w = idx - h * Wdim;
            const bool inblk = (h >= y0) & (h < y0 + 7) & (w >= x0) & (w < x0 + 2);
            const bool msk = (val == m) | inblk;
            // match ref rounding: x - (0.9*x); separate mul then sub
            const float t = SUPPRESS * val;
            res[j] = msk ? (val - t) : val;
        }
        return res;
    };

    f4 r0 = proc(v0, lane);
    f4 r1 = proc(v1, lane + 64);
    f4 r2 = proc(v2, lane + 128);
    __builtin_nontemporal_store(r0, &op[lane]);
    __builtin_nontemporal_store(r1, &op[lane + 64]);
    __builtin_nontemporal_store(r2, &op[lane + 128]);
    if (extra) {
        f4 r3 = proc(v3, lane + 192);
        __builtin_nontemporal_store(r3, &op[lane + 192]);
    }
}

extern "C" void kernel_launch(void* const* d_in, const int* in_sizes, int n_in,
                              void* d_out, int out_size, void* d_ws, size_t ws_size,
                              hipStream_t stream) {
    const float* x      = (const float*)d_in[0];
    const int*   mask_y = (const int*)d_in[1];
    const int*   mask_x = (const int*)d_in[2];
    float*       out    = (float*)d_out;

    const int nch = in_sizes[1];              // B*C = 32768
    const int waves_per_block = 4;            // 256 threads
    const int nblocks = (nch + waves_per_block - 1) / waves_per_block;

    hipLaunchKernelGGL(selectdropmax_kernel,
                       dim3(nblocks), dim3(256), 0, stream,
                       x, mask_y, mask_x, out, nch);
}